// Round 4
// baseline (515.072 us; speedup 1.0000x reference)
//
#include <hip/hip_runtime.h>

typedef __attribute__((ext_vector_type(8))) short short8;
typedef __attribute__((ext_vector_type(4))) float f32x4;
typedef __attribute__((ext_vector_type(4))) ushort u16x4;

constexpr int NN = 10000;
constexpr int NE = 160000;
constexpr int NT = NE / 16;                    // 10000 edge-tiles
constexpr float EPSV = 1e-5f;
constexpr float INV3 = 0.57735026918962576f;   // 1/sqrt(3)
constexpr float ALPHA = 0.20412414523193152f;  // 1/sqrt(16+8)

__device__ __forceinline__ ushort f2bf(float x) {
  unsigned u = __float_as_uint(x);
  u += 0x7fffu + ((u >> 16) & 1u);
  return (ushort)(u >> 16);
}
__device__ __forceinline__ float bf2f(ushort u) {
  return __uint_as_float(((unsigned)u) << 16);
}
__device__ __forceinline__ f32x4 mfma16(short8 a, short8 b, f32x4 c) {
  return __builtin_amdgcn_mfma_f32_16x16x32_bf16(a, b, c, 0, 0, 0);
}

// tp element type abstraction (float normally; bf16 only in tiny-ws fallback)
template <typename T> struct TPS;
template <> struct TPS<float> {
  static __device__ __forceinline__ void st4(float* p, f32x4 v) { *(f32x4*)p = v; }
  static __device__ __forceinline__ float ld(const float* p) { return *p; }
};
template <> struct TPS<ushort> {
  static __device__ __forceinline__ void st4(ushort* p, f32x4 v) {
    u16x4 o;
#pragma unroll
    for (int j = 0; j < 4; ++j) o[j] = f2bf(v[j]);
    *(u16x4*)p = o;
  }
  static __device__ __forceinline__ float ld(const ushort* p) { return bf2f(*p); }
};

// ---------------- K0: W2 -> bf16 A-frag layout; b2 nonzero flag ----------------
__global__ __launch_bounds__(64) void prep_w2(const float* __restrict__ w2,
                                              const float* __restrict__ b2,
                                              short8* __restrict__ w2bf,
                                              float* __restrict__ flag) {
  int b = blockIdx.x;
  int lane = threadIdx.x;
  if (b < 72) {
    int jt = b >> 1, kc = b & 1;
    int g = lane >> 4, c = lane & 15;
    short8 v;
#pragma unroll
    for (int j = 0; j < 8; ++j)
      v[j] = (short)f2bf(w2[(kc * 32 + 8 * g + j) * 576 + jt * 16 + c]);
    w2bf[(jt * 2 + kc) * 64 + lane] = v;
  } else {
    float m = 0.f;
    for (int i = lane; i < 576; i += 64) m = fmaxf(m, fabsf(b2[i]));
#pragma unroll
    for (int off = 1; off < 64; off <<= 1) m = fmaxf(m, __shfl_xor(m, off));
    if (lane == 0) *flag = m;
  }
}

// ---------------- K1: h = relu(ef @ W1 + b1) -> bf16 h-fragments (verified) ----------------
__global__ __launch_bounds__(256) void mlp1_kernel(
    const float* __restrict__ ef, const float* __restrict__ w1,
    const float* __restrict__ b1, short8* __restrict__ hfrag,
    float* __restrict__ efout, int do_copy)
{
  __shared__ short8 w1f[512];
  __shared__ ushort hlds[4][16 * 72];

  for (int t = threadIdx.x; t < 512; t += 256) {
    int tile = t >> 6, l = t & 63;
    int nt = tile >> 1, kc = tile & 1;
    int gg = l >> 4, cc = l & 15;
    short8 v;
#pragma unroll
    for (int j = 0; j < 8; ++j)
      v[j] = (short)f2bf(w1[(kc * 32 + 8 * gg + j) * 64 + nt * 16 + cc]);
    w1f[t] = v;
  }
  __syncthreads();

  const int lane = threadIdx.x & 63, wid = threadIdx.x >> 6;
  const int g = lane >> 4, c = lane & 15;
  const long tile = (long)blockIdx.x * 4 + wid;
  const long ebase = tile * 16;

  short8 af[2];
  const float* rowp = ef + (ebase + c) * 64;
#pragma unroll
  for (int kc = 0; kc < 2; ++kc) {
    const f32x4* p = (const f32x4*)(rowp + kc * 32 + 8 * g);
    f32x4 lo = p[0], hi = p[1];
    if (do_copy) {
      f32x4* q = (f32x4*)(efout + (ebase + c) * 64 + kc * 32 + 8 * g);
      q[0] = lo; q[1] = hi;
    }
    short8 v;
#pragma unroll
    for (int j = 0; j < 4; ++j) { v[j] = (short)f2bf(lo[j]); v[4 + j] = (short)f2bf(hi[j]); }
    af[kc] = v;
  }

  f32x4 acc[4] = {};
#pragma unroll
  for (int nt = 0; nt < 4; ++nt)
#pragma unroll
    for (int kc = 0; kc < 2; ++kc)
      acc[nt] = mfma16(af[kc], w1f[(nt * 2 + kc) * 64 + lane], acc[nt]);

#pragma unroll
  for (int nt = 0; nt < 4; ++nt) {
    float bv = b1[nt * 16 + c];
#pragma unroll
    for (int q = 0; q < 4; ++q) {
      float h = fmaxf(acc[nt][q] + bv, 0.f);
      hlds[wid][(4 * g + q) * 72 + nt * 16 + c] = f2bf(h);
    }
  }
#pragma unroll
  for (int kc = 0; kc < 2; ++kc) {
    short8 hv = *(const short8*)&hlds[wid][c * 72 + kc * 32 + 8 * g];
    hfrag[(tile * 2 + kc) * 64 + lane] = hv;
  }
}

// ---------------- K2: per-wave 16-edge tile -> dense tp[E][40], no atomics ----------------
constexpr unsigned SM_W2 = 4608 * 16;  // 73728 B

template <typename T>
__global__ __launch_bounds__(512, 4) void conv_kernel(
    const short8* __restrict__ hfrag, const short8* __restrict__ w2bf,
    const float* __restrict__ b2, const float* __restrict__ nf,
    const float* __restrict__ sh, const int* __restrict__ ei,
    T* __restrict__ tp, const float* __restrict__ flagp)
{
  extern __shared__ char smem[];
  short8* w2lds = (short8*)smem;
  const int tid = threadIdx.x;
  for (int i = tid; i < 4608; i += 512) w2lds[i] = w2bf[i];
  const bool hasb2 = (*flagp != 0.f);
  __syncthreads();

  const int lane = tid & 63, wid = tid >> 6;
  const int g = lane >> 4, c = lane & 15;
  const int gh = g >> 1;

  for (int t = blockIdx.x * 8 + wid; t < NT; t += gridDim.x * 8) {
    const int eg = t * 16 + c;
    const int dstc = ei[eg];
    const float* __restrict__ nfd = nf + (size_t)dstc * 40;

    // per-lane raw node features (L2-resident, 4-way lane broadcast)
    float x0v[16];
#pragma unroll
    for (int p = 0; p < 4; ++p) {
      f32x4 r = *(const f32x4*)(nfd + p * 4);
#pragma unroll
      for (int j = 0; j < 4; ++j) x0v[p * 4 + j] = r[j];
    }
    float x1f[24];
#pragma unroll
    for (int p = 0; p < 6; ++p) {
      f32x4 r = *(const f32x4*)(nfd + 16 + p * 4);
#pragma unroll
      for (int j = 0; j < 4; ++j) x1f[p * 4 + j] = r[j];
    }
    f32x4 shv = *(const f32x4*)(sh + (size_t)eg * 4);
    const float sh0 = shv[0];

    float a1v[8];  // inv3 * (x1[u] . sh1)
#pragma unroll
    for (int u = 0; u < 8; ++u)
      a1v[u] = INV3 * (x1f[3 * u] * shv[1] + x1f[3 * u + 1] * shv[2] +
                       x1f[3 * u + 2] * shv[3]);

    const short8 h0 = hfrag[(t * 2 + 0) * 64 + lane];
    const short8 h1 = hfrag[(t * 2 + 1) * 64 + lane];

    f32x4 out0acc = {0.f, 0.f, 0.f, 0.f};
    f32x4 c0acc = {0.f, 0.f, 0.f, 0.f};
    f32x4 c1acc[3] = {};

    if (__builtin_expect(hasb2, 0)) {  // cold general-correctness path (b2 == 0 in bench)
      const int gl = g & 1;
      float bsc = (gh == 0) ? 1.f : 0.f;
#pragma unroll
      for (int u = 0; u < 16; ++u)
#pragma unroll
        for (int q = 0; q < 4; ++q) {
          out0acc[q] += sh0 * x0v[u] * b2[u * 16 + 4 * g + q];
          c0acc[q] += bsc * x0v[u] * b2[384 + u * 8 + 4 * gl + q];
        }
#pragma unroll
      for (int u = 0; u < 8; ++u) {
#pragma unroll
        for (int q = 0; q < 4; ++q) out0acc[q] += a1v[u] * b2[256 + u * 16 + 4 * g + q];
#pragma unroll
        for (int i = 0; i < 3; ++i)
#pragma unroll
          for (int q = 0; q < 4; ++q)
            c1acc[i][q] += bsc * x1f[3 * u + i] * b2[512 + u * 8 + 4 * gl + q];
      }
    }

    // j-GEMM: D[j=jt*16+4g+q][edge=c], lane-local tensor-product consume
#pragma unroll
    for (int jt = 0; jt < 16; ++jt) {          // w00: u=jt
      f32x4 d = {0.f, 0.f, 0.f, 0.f};
      d = mfma16(w2lds[(jt * 2 + 0) * 64 + lane], h0, d);
      d = mfma16(w2lds[(jt * 2 + 1) * 64 + lane], h1, d);
      float a = sh0 * x0v[jt];
#pragma unroll
      for (int q = 0; q < 4; ++q) out0acc[q] = fmaf(a, d[q], out0acc[q]);
    }
#pragma unroll
    for (int jt = 16; jt < 24; ++jt) {         // w11: u=jt-16
      f32x4 d = {0.f, 0.f, 0.f, 0.f};
      d = mfma16(w2lds[(jt * 2 + 0) * 64 + lane], h0, d);
      d = mfma16(w2lds[(jt * 2 + 1) * 64 + lane], h1, d);
      float a = a1v[jt - 16];
#pragma unroll
      for (int q = 0; q < 4; ++q) out0acc[q] = fmaf(a, d[q], out0acc[q]);
    }
#pragma unroll
    for (int jt = 24; jt < 32; ++jt) {         // w01: u=2(jt-24)+gh
      f32x4 d = {0.f, 0.f, 0.f, 0.f};
      d = mfma16(w2lds[(jt * 2 + 0) * 64 + lane], h0, d);
      d = mfma16(w2lds[(jt * 2 + 1) * 64 + lane], h1, d);
      float a = gh ? x0v[2 * (jt - 24) + 1] : x0v[2 * (jt - 24)];
#pragma unroll
      for (int q = 0; q < 4; ++q) c0acc[q] = fmaf(a, d[q], c0acc[q]);
    }
#pragma unroll
    for (int jt = 32; jt < 36; ++jt) {         // w10: u=2(jt-32)+gh
      f32x4 d = {0.f, 0.f, 0.f, 0.f};
      d = mfma16(w2lds[(jt * 2 + 0) * 64 + lane], h0, d);
      d = mfma16(w2lds[(jt * 2 + 1) * 64 + lane], h1, d);
#pragma unroll
      for (int i = 0; i < 3; ++i) {
        float a = gh ? x1f[(2 * (jt - 32) + 1) * 3 + i] : x1f[(2 * (jt - 32)) * 3 + i];
#pragma unroll
        for (int q = 0; q < 4; ++q) c1acc[i][q] = fmaf(a, d[q], c1acc[i][q]);
      }
    }

    // fold gh halves (lane ^ 32)
#pragma unroll
    for (int q = 0; q < 4; ++q) c0acc[q] += __shfl_xor(c0acc[q], 32);
#pragma unroll
    for (int i = 0; i < 3; ++i)
#pragma unroll
      for (int q = 0; q < 4; ++q) c1acc[i][q] += __shfl_xor(c1acc[i][q], 32);

    // dense coalesced store: tp[edge][40]
    T* tpr = tp + (size_t)eg * 40;
    f32x4 o0;
#pragma unroll
    for (int q = 0; q < 4; ++q) o0[q] = ALPHA * out0acc[q];
    TPS<T>::st4(tpr + 4 * g, o0);
    if (g < 2) {
      float wv[12];
#pragma unroll
      for (int q = 0; q < 4; ++q)
#pragma unroll
        for (int i = 0; i < 3; ++i)
          wv[q * 3 + i] = ALPHA * (shv[1 + i] * c0acc[q] + sh0 * c1acc[i][q]);
#pragma unroll
      for (int p = 0; p < 3; ++p) {
        f32x4 v = {wv[4 * p], wv[4 * p + 1], wv[4 * p + 2], wv[4 * p + 3]};
        TPS<T>::st4(tpr + 16 + 12 * g + 4 * p, v);
      }
    }
  }
}

// ---------------- CSR build ----------------
__global__ __launch_bounds__(256) void hist_kernel(const int* __restrict__ ei,
                                                   int* __restrict__ deg) {
  for (int e = blockIdx.x * 256 + threadIdx.x; e < NE; e += gridDim.x * 256)
    atomicAdd(&deg[ei[NE + e]], 1);
}

__global__ __launch_bounds__(1024) void scan_kernel(const int* __restrict__ deg,
                                                    int* __restrict__ rowoff,
                                                    int* __restrict__ wcur) {
  __shared__ int s[1024];
  int t = threadIdx.x;
  int base = t * 10;
  int sum = 0;
#pragma unroll
  for (int j = 0; j < 10; ++j) { int n = base + j; sum += (n < NN) ? deg[n] : 0; }
  s[t] = sum;
  __syncthreads();
  for (int off = 1; off < 1024; off <<= 1) {
    int v = (t >= off) ? s[t - off] : 0;
    __syncthreads();
    s[t] += v;
    __syncthreads();
  }
  int run = s[t] - sum;
#pragma unroll
  for (int j = 0; j < 10; ++j) {
    int n = base + j;
    if (n < NN) { rowoff[n] = run; wcur[n] = run; run += deg[n]; }
  }
  if (t == 1023) rowoff[NN] = s[1023];
}

__global__ __launch_bounds__(256) void fill_kernel(const int* __restrict__ ei,
                                                   int* __restrict__ wcur,
                                                   int* __restrict__ elist) {
  for (int e = blockIdx.x * 256 + threadIdx.x; e < NE; e += gridDim.x * 256) {
    int pos = atomicAdd(&wcur[ei[NE + e]], 1);
    elist[pos] = e;
  }
}

// ---------------- gather: segment mean + residual + stats ----------------
template <typename T>
__global__ __launch_bounds__(256) void gather_kernel(
    const T* __restrict__ tp, const int* __restrict__ rowoff,
    const int* __restrict__ elist, const float* __restrict__ nf,
    float* __restrict__ pre, float* __restrict__ stats)
{
  __shared__ float ls[40];
  if (threadIdx.x < 40) ls[threadIdx.x] = 0.f;
  __syncthreads();
  const int wid = threadIdx.x >> 6, lane = threadIdx.x & 63;
  const int n = blockIdx.x * 4 + wid;
  if (n < NN && lane < 40) {
    int r0 = rowoff[n], r1 = rowoff[n + 1];
    float s = 0.f;
    for (int k = r0; k < r1; ++k) {
      int e = elist[k];
      s += TPS<T>::ld(tp + (size_t)e * 40 + lane);
    }
    float val = s / fmaxf((float)(r1 - r0), 1.f) + nf[(size_t)n * 40 + lane];
    pre[(size_t)n * 40 + lane] = val;
    if (lane < 16) {
      atomicAdd(&ls[lane], val);
      atomicAdd(&ls[16 + lane], val * val);
    } else {
      int u = (lane - 16) / 3;
      atomicAdd(&ls[32 + u], val * val);
    }
  }
  __syncthreads();
  if (threadIdx.x < 40) atomicAdd(&stats[threadIdx.x], ls[threadIdx.x]);
}

__global__ __launch_bounds__(256) void node_pass2(
    const float* __restrict__ pre, const float* __restrict__ stats,
    const float* __restrict__ bnws, const float* __restrict__ bnbs,
    const float* __restrict__ bnwv, float* __restrict__ out)
{
  int idx = blockIdx.x * blockDim.x + threadIdx.x;
  if (idx >= NN * 40) return;
  int n = idx / 40;
  int c = idx - n * 40;
  float val = pre[idx];
  constexpr float invN = 1.0f / NN;
  if (c < 16) {
    float mu = stats[c] * invN;
    float var = stats[16 + c] * invN - mu * mu;
    out[idx] = (val - mu) * (rsqrtf(var + EPSV) * bnws[c]) + bnbs[c];
  } else {
    int u = (c - 16) / 3;
    float vn = stats[32 + u] * (invN / 3.0f);
    out[idx] = val * (rsqrtf(vn + EPSV) * bnwv[u]);
  }
}

__global__ __launch_bounds__(256) void copy_ef(const f32x4* __restrict__ src,
                                               f32x4* __restrict__ dst) {
  const int n4 = NE * 64 / 4;
  for (int i = blockIdx.x * blockDim.x + threadIdx.x; i < n4;
       i += gridDim.x * blockDim.x)
    dst[i] = src[i];
}

extern "C" void kernel_launch(void* const* d_in, const int* in_sizes, int n_in,
                              void* d_out, int out_size, void* d_ws, size_t ws_size,
                              hipStream_t stream) {
  (void)in_sizes; (void)n_in; (void)out_size;
  const float* nf   = (const float*)d_in[0];
  const float* ef   = (const float*)d_in[1];
  const float* sh   = (const float*)d_in[2];
  const int*   ei   = (const int*)d_in[3];
  const float* w1   = (const float*)d_in[4];
  const float* b1   = (const float*)d_in[5];
  const float* w2   = (const float*)d_in[6];
  const float* b2   = (const float*)d_in[7];
  const float* bnws = (const float*)d_in[8];
  const float* bnbs = (const float*)d_in[9];
  const float* bnwv = (const float*)d_in[10];

  float* out = (float*)d_out;
  float* efout = out + (size_t)NN * 40;

  // ws layout
  char* w = (char*)d_ws;
  int* deg     = (int*)w;                               // NN      (memset)
  float* stats = (float*)(w + (size_t)NN * 4);          // 48      (memset)
  float* flag  = stats + 40;
  int* rowoff  = (int*)(w + (size_t)NN * 4 + 192);      // NN+1
  int* wcur    = rowoff + NN + 1;
  int* elist   = wcur + NN;                             // NE
  float* pre   = (float*)(elist + NE);                  // NN*40
  size_t base  = ((size_t)((char*)(pre + (size_t)NN * 40) - w) + 255) & ~(size_t)255;
  short8* w2bf = (short8*)(w + base);                   // 73728 B
  size_t tpoff = (base + SM_W2 + 255) & ~(size_t)255;

  const size_t TPB_F32 = (size_t)NE * 40 * 4;           // 25.6 MB
  const size_t HFB     = (size_t)NT * 128 * 16;         // 20.48 MB
  const size_t needA = tpoff + TPB_F32 + HFB;
  const size_t needB = tpoff + TPB_F32;
  const size_t needD = tpoff;

  hipMemsetAsync(d_ws, 0, (size_t)NN * 4 + 192, stream);
  hipFuncSetAttribute((const void*)conv_kernel<float>,
                      hipFuncAttributeMaxDynamicSharedMemorySize, SM_W2);
  hipFuncSetAttribute((const void*)conv_kernel<ushort>,
                      hipFuncAttributeMaxDynamicSharedMemorySize, SM_W2);

  prep_w2<<<73, 64, 0, stream>>>(w2, b2, w2bf, flag);

  const int gblocks = 2500;  // gather: 4 nodes/block
  const int pblocks = (NN * 40 + 255) / 256;

  if (ws_size >= needA) {            // Plan A: everything in ws
    float* tp = (float*)(w + tpoff);
    short8* hfrag = (short8*)(w + tpoff + TPB_F32);
    mlp1_kernel<<<2500, 256, 0, stream>>>(ef, w1, b1, hfrag, efout, 1);
    hist_kernel<<<625, 256, 0, stream>>>(ei, deg);
    scan_kernel<<<1, 1024, 0, stream>>>(deg, rowoff, wcur);
    fill_kernel<<<625, 256, 0, stream>>>(ei, wcur, elist);
    conv_kernel<float><<<512, 512, SM_W2, stream>>>(hfrag, w2bf, b2, nf, sh, ei, tp, flag);
    gather_kernel<float><<<gblocks, 256, 0, stream>>>(tp, rowoff, elist, nf, pre, stats);
    node_pass2<<<pblocks, 256, 0, stream>>>(pre, stats, bnws, bnbs, bnwv, out);
  } else if (ws_size >= needB) {     // Plan B: hfrag borrows efout, copy later
    float* tp = (float*)(w + tpoff);
    short8* hfrag = (short8*)efout;
    mlp1_kernel<<<2500, 256, 0, stream>>>(ef, w1, b1, hfrag, efout, 0);
    hist_kernel<<<625, 256, 0, stream>>>(ei, deg);
    scan_kernel<<<1, 1024, 0, stream>>>(deg, rowoff, wcur);
    fill_kernel<<<625, 256, 0, stream>>>(ei, wcur, elist);
    conv_kernel<float><<<512, 512, SM_W2, stream>>>(hfrag, w2bf, b2, nf, sh, ei, tp, flag);
    gather_kernel<float><<<gblocks, 256, 0, stream>>>(tp, rowoff, elist, nf, pre, stats);
    node_pass2<<<pblocks, 256, 0, stream>>>(pre, stats, bnws, bnbs, bnwv, out);
    copy_ef<<<2048, 256, 0, stream>>>((const f32x4*)ef, (f32x4*)efout);
  } else {                           // Plan D: bf16 tp + hfrag both in efout region
    (void)needD;
    ushort* tp = (ushort*)efout;                              // 12.8 MB
    short8* hfrag = (short8*)((char*)efout + (size_t)NE * 40 * 2);
    mlp1_kernel<<<2500, 256, 0, stream>>>(ef, w1, b1, hfrag, efout, 0);
    hist_kernel<<<625, 256, 0, stream>>>(ei, deg);
    scan_kernel<<<1, 1024, 0, stream>>>(deg, rowoff, wcur);
    fill_kernel<<<625, 256, 0, stream>>>(ei, wcur, elist);
    conv_kernel<ushort><<<512, 512, SM_W2, stream>>>(hfrag, w2bf, b2, nf, sh, ei, tp, flag);
    gather_kernel<ushort><<<gblocks, 256, 0, stream>>>(tp, rowoff, elist, nf, pre, stats);
    node_pass2<<<pblocks, 256, 0, stream>>>(pre, stats, bnws, bnbs, bnwv, out);
    copy_ef<<<2048, 256, 0, stream>>>((const f32x4*)ef, (f32x4*)efout);
  }
}

// Round 6
// 315.580 us; speedup vs baseline: 1.6321x; 1.6321x over previous
//
#include <hip/hip_runtime.h>

typedef __attribute__((ext_vector_type(8))) short short8;
typedef __attribute__((ext_vector_type(4))) float f32x4;
typedef __attribute__((ext_vector_type(4))) ushort u16x4;

constexpr int NN = 10000;
constexpr int NE = 160000;
constexpr int NT = NE / 16;                    // 10000 edge-tiles
constexpr float EPSV = 1e-5f;
constexpr float INV3 = 0.57735026918962576f;   // 1/sqrt(3)
constexpr float ALPHA = 0.20412414523193152f;  // 1/sqrt(16+8)

__device__ __forceinline__ ushort f2bf(float x) {
  unsigned u = __float_as_uint(x);
  u += 0x7fffu + ((u >> 16) & 1u);
  return (ushort)(u >> 16);
}
__device__ __forceinline__ float bf2f(ushort u) {
  return __uint_as_float(((unsigned)u) << 16);
}
__device__ __forceinline__ f32x4 mfma16(short8 a, short8 b, f32x4 c) {
  return __builtin_amdgcn_mfma_f32_16x16x32_bf16(a, b, c, 0, 0, 0);
}

template <typename T> struct TPS;
template <> struct TPS<float> {
  static __device__ __forceinline__ void st4(float* p, f32x4 v) { *(f32x4*)p = v; }
  static __device__ __forceinline__ float ld(const float* p) { return *p; }
};
template <> struct TPS<ushort> {
  static __device__ __forceinline__ void st4(ushort* p, f32x4 v) {
    u16x4 o;
#pragma unroll
    for (int j = 0; j < 4; ++j) o[j] = f2bf(v[j]);
    *(u16x4*)p = o;
  }
  static __device__ __forceinline__ float ld(const ushort* p) { return bf2f(*p); }
};

// ---------------- K0: W2 -> bf16 A-frag layout ----------------
__global__ __launch_bounds__(64) void prep_w2(const float* __restrict__ w2,
                                              short8* __restrict__ w2bf) {
  int b = blockIdx.x;          // 72 = 36 jt * 2 kc
  int lane = threadIdx.x;
  int jt = b >> 1, kc = b & 1;
  int g = lane >> 4, c = lane & 15;
  short8 v;
#pragma unroll
  for (int j = 0; j < 8; ++j)
    v[j] = (short)f2bf(w2[(kc * 32 + 8 * g + j) * 576 + jt * 16 + c]);
  w2bf[(jt * 2 + kc) * 64 + lane] = v;
}

// ---------------- K1: h = relu(ef @ W1 + b1) -> bf16 h-fragments (verified) ----------------
__global__ __launch_bounds__(256) void mlp1_kernel(
    const float* __restrict__ ef, const float* __restrict__ w1,
    const float* __restrict__ b1, short8* __restrict__ hfrag,
    float* __restrict__ efout, int do_copy)
{
  __shared__ short8 w1f[512];
  __shared__ ushort hlds[4][16 * 72];

  for (int t = threadIdx.x; t < 512; t += 256) {
    int tile = t >> 6, l = t & 63;
    int nt = tile >> 1, kc = tile & 1;
    int gg = l >> 4, cc = l & 15;
    short8 v;
#pragma unroll
    for (int j = 0; j < 8; ++j)
      v[j] = (short)f2bf(w1[(kc * 32 + 8 * gg + j) * 64 + nt * 16 + cc]);
    w1f[t] = v;
  }
  __syncthreads();

  const int lane = threadIdx.x & 63, wid = threadIdx.x >> 6;
  const int g = lane >> 4, c = lane & 15;
  const long tile = (long)blockIdx.x * 4 + wid;
  const long ebase = tile * 16;

  short8 af[2];
  const float* rowp = ef + (ebase + c) * 64;
#pragma unroll
  for (int kc = 0; kc < 2; ++kc) {
    const f32x4* p = (const f32x4*)(rowp + kc * 32 + 8 * g);
    f32x4 lo = p[0], hi = p[1];
    if (do_copy) {
      f32x4* q = (f32x4*)(efout + (ebase + c) * 64 + kc * 32 + 8 * g);
      q[0] = lo; q[1] = hi;
    }
    short8 v;
#pragma unroll
    for (int j = 0; j < 4; ++j) { v[j] = (short)f2bf(lo[j]); v[4 + j] = (short)f2bf(hi[j]); }
    af[kc] = v;
  }

  f32x4 acc[4] = {};
#pragma unroll
  for (int nt = 0; nt < 4; ++nt)
#pragma unroll
    for (int kc = 0; kc < 2; ++kc)
      acc[nt] = mfma16(af[kc], w1f[(nt * 2 + kc) * 64 + lane], acc[nt]);

#pragma unroll
  for (int nt = 0; nt < 4; ++nt) {
    float bv = b1[nt * 16 + c];
#pragma unroll
    for (int q = 0; q < 4; ++q) {
      float h = fmaxf(acc[nt][q] + bv, 0.f);
      hlds[wid][(4 * g + q) * 72 + nt * 16 + c] = f2bf(h);
    }
  }
#pragma unroll
  for (int kc = 0; kc < 2; ++kc) {
    short8 hv = *(const short8*)&hlds[wid][c * 72 + kc * 32 + 8 * g];
    hfrag[(tile * 2 + kc) * 64 + lane] = hv;
  }
}

// ---------------- K2: per-wave 16-edge tile -> dense tp[E][40] ----------------
// Bias folded into MFMA C-operand: d = W2^T h + b2  (exact; each lane's j
// carries its own bias element; the gh-fold sums DIFFERENT u's, no dup).
constexpr unsigned SM_W2 = 4608 * 16;              // 73728 B
constexpr unsigned SM_TOTAL = SM_W2 + 576 * 4;     // + b2 table = 76032 B

template <typename T>
__global__ __launch_bounds__(512, 1) void conv_kernel(
    const short8* __restrict__ hfrag, const short8* __restrict__ w2bf,
    const float* __restrict__ b2, const float* __restrict__ nf,
    const float* __restrict__ sh, const int* __restrict__ ei,
    T* __restrict__ tp)
{
  extern __shared__ char smem[];
  short8* w2lds = (short8*)smem;
  float* b2lds = (float*)(smem + SM_W2);
  const int tid = threadIdx.x;
  for (int i = tid; i < 4608; i += 512) w2lds[i] = w2bf[i];
  for (int i = tid; i < 576; i += 512) b2lds[i] = b2[i];   // FIX r5: full 576, not tid<576
  __syncthreads();

  const int lane = tid & 63, wid = tid >> 6;
  const int g = lane >> 4, c = lane & 15;
  const int gh = g >> 1;

  for (int t = blockIdx.x * 8 + wid; t < NT; t += gridDim.x * 8) {
    const int eg = t * 16 + c;
    const int dstc = ei[eg];
    const float* __restrict__ nfd = nf + (size_t)dstc * 40;

    float x0v[16];
#pragma unroll
    for (int p = 0; p < 4; ++p) {
      f32x4 r = *(const f32x4*)(nfd + p * 4);
#pragma unroll
      for (int j = 0; j < 4; ++j) x0v[p * 4 + j] = r[j];
    }
    f32x4 shv = *(const f32x4*)(sh + (size_t)eg * 4);
    const float sh0 = shv[0];

    // consume x1 row into a1v (all u) and x1v (u = 2jt+gh only)
    float a1v[8];
    float x1v[3][4];
    {
      float x1f[24];
#pragma unroll
      for (int p = 0; p < 6; ++p) {
        f32x4 r = *(const f32x4*)(nfd + 16 + p * 4);
#pragma unroll
        for (int j = 0; j < 4; ++j) x1f[p * 4 + j] = r[j];
      }
#pragma unroll
      for (int u = 0; u < 8; ++u)
        a1v[u] = INV3 * (x1f[3 * u] * shv[1] + x1f[3 * u + 1] * shv[2] +
                         x1f[3 * u + 2] * shv[3]);
#pragma unroll
      for (int jt = 0; jt < 4; ++jt)
#pragma unroll
        for (int i = 0; i < 3; ++i)
          x1v[i][jt] = gh ? x1f[(2 * jt + 1) * 3 + i] : x1f[(2 * jt) * 3 + i];
    }

    const short8 h0 = hfrag[(t * 2 + 0) * 64 + lane];
    const short8 h1 = hfrag[(t * 2 + 1) * 64 + lane];

    f32x4 out0acc = {0.f, 0.f, 0.f, 0.f};
    f32x4 c0acc = {0.f, 0.f, 0.f, 0.f};
    f32x4 c1acc[3] = {};

#pragma unroll
    for (int jt = 0; jt < 16; ++jt) {          // w00: u=jt
      f32x4 d = *(const f32x4*)&b2lds[jt * 16 + 4 * g];
      d = mfma16(w2lds[(jt * 2 + 0) * 64 + lane], h0, d);
      d = mfma16(w2lds[(jt * 2 + 1) * 64 + lane], h1, d);
      float a = sh0 * x0v[jt];
#pragma unroll
      for (int q = 0; q < 4; ++q) out0acc[q] = fmaf(a, d[q], out0acc[q]);
    }
#pragma unroll
    for (int jt = 16; jt < 24; ++jt) {         // w11: u=jt-16
      f32x4 d = *(const f32x4*)&b2lds[jt * 16 + 4 * g];
      d = mfma16(w2lds[(jt * 2 + 0) * 64 + lane], h0, d);
      d = mfma16(w2lds[(jt * 2 + 1) * 64 + lane], h1, d);
      float a = a1v[jt - 16];
#pragma unroll
      for (int q = 0; q < 4; ++q) out0acc[q] = fmaf(a, d[q], out0acc[q]);
    }
#pragma unroll
    for (int jt = 24; jt < 32; ++jt) {         // w01: u=2(jt-24)+gh
      f32x4 d = *(const f32x4*)&b2lds[jt * 16 + 4 * g];
      d = mfma16(w2lds[(jt * 2 + 0) * 64 + lane], h0, d);
      d = mfma16(w2lds[(jt * 2 + 1) * 64 + lane], h1, d);
      float a = gh ? x0v[2 * (jt - 24) + 1] : x0v[2 * (jt - 24)];
#pragma unroll
      for (int q = 0; q < 4; ++q) c0acc[q] = fmaf(a, d[q], c0acc[q]);
    }
#pragma unroll
    for (int jt = 32; jt < 36; ++jt) {         // w10: u=2(jt-32)+gh
      f32x4 d = *(const f32x4*)&b2lds[jt * 16 + 4 * g];
      d = mfma16(w2lds[(jt * 2 + 0) * 64 + lane], h0, d);
      d = mfma16(w2lds[(jt * 2 + 1) * 64 + lane], h1, d);
#pragma unroll
      for (int i = 0; i < 3; ++i) {
        float a = x1v[i][jt - 32];
#pragma unroll
        for (int q = 0; q < 4; ++q) c1acc[i][q] = fmaf(a, d[q], c1acc[i][q]);
      }
    }

    // fold gh halves (lane ^ 32)
#pragma unroll
    for (int q = 0; q < 4; ++q) c0acc[q] += __shfl_xor(c0acc[q], 32);
#pragma unroll
    for (int i = 0; i < 3; ++i)
#pragma unroll
      for (int q = 0; q < 4; ++q) c1acc[i][q] += __shfl_xor(c1acc[i][q], 32);

    // dense coalesced store: tp[edge][40]
    T* tpr = tp + (size_t)eg * 40;
    f32x4 o0;
#pragma unroll
    for (int q = 0; q < 4; ++q) o0[q] = ALPHA * out0acc[q];
    TPS<T>::st4(tpr + 4 * g, o0);
    if (g < 2) {
      float wv[12];
#pragma unroll
      for (int q = 0; q < 4; ++q)
#pragma unroll
        for (int i = 0; i < 3; ++i)
          wv[q * 3 + i] = ALPHA * (shv[1 + i] * c0acc[q] + sh0 * c1acc[i][q]);
#pragma unroll
      for (int p = 0; p < 3; ++p) {
        f32x4 v = {wv[4 * p], wv[4 * p + 1], wv[4 * p + 2], wv[4 * p + 3]};
        TPS<T>::st4(tpr + 16 + 12 * g + 4 * p, v);
      }
    }
  }
}

// ---------------- CSR build ----------------
__global__ __launch_bounds__(256) void hist_kernel(const int* __restrict__ ei,
                                                   int* __restrict__ deg) {
  for (int e = blockIdx.x * 256 + threadIdx.x; e < NE; e += gridDim.x * 256)
    atomicAdd(&deg[ei[NE + e]], 1);
}

__global__ __launch_bounds__(1024) void scan_kernel(const int* __restrict__ deg,
                                                    int* __restrict__ rowoff,
                                                    int* __restrict__ wcur) {
  __shared__ int s[1024];
  int t = threadIdx.x;
  int base = t * 10;
  int sum = 0;
#pragma unroll
  for (int j = 0; j < 10; ++j) { int n = base + j; sum += (n < NN) ? deg[n] : 0; }
  s[t] = sum;
  __syncthreads();
  for (int off = 1; off < 1024; off <<= 1) {
    int v = (t >= off) ? s[t - off] : 0;
    __syncthreads();
    s[t] += v;
    __syncthreads();
  }
  int run = s[t] - sum;
#pragma unroll
  for (int j = 0; j < 10; ++j) {
    int n = base + j;
    if (n < NN) { rowoff[n] = run; wcur[n] = run; run += deg[n]; }
  }
  if (t == 1023) rowoff[NN] = s[1023];
}

__global__ __launch_bounds__(256) void fill_kernel(const int* __restrict__ ei,
                                                   int* __restrict__ wcur,
                                                   int* __restrict__ elist) {
  for (int e = blockIdx.x * 256 + threadIdx.x; e < NE; e += gridDim.x * 256) {
    int pos = atomicAdd(&wcur[ei[NE + e]], 1);
    elist[pos] = e;
  }
}

// ---------------- gather: segment mean + residual + stats ----------------
template <typename T>
__global__ __launch_bounds__(256) void gather_kernel(
    const T* __restrict__ tp, const int* __restrict__ rowoff,
    const int* __restrict__ elist, const float* __restrict__ nf,
    float* __restrict__ pre, float* __restrict__ stats)
{
  __shared__ float ls[40];
  if (threadIdx.x < 40) ls[threadIdx.x] = 0.f;
  __syncthreads();
  const int wid = threadIdx.x >> 6, lane = threadIdx.x & 63;
  const int n = blockIdx.x * 4 + wid;
  if (n < NN && lane < 40) {
    int r0 = rowoff[n], r1 = rowoff[n + 1];
    float s = 0.f;
    for (int k = r0; k < r1; ++k) {
      int e = elist[k];
      s += TPS<T>::ld(tp + (size_t)e * 40 + lane);
    }
    float val = s / fmaxf((float)(r1 - r0), 1.f) + nf[(size_t)n * 40 + lane];
    pre[(size_t)n * 40 + lane] = val;
    if (lane < 16) {
      atomicAdd(&ls[lane], val);
      atomicAdd(&ls[16 + lane], val * val);
    } else {
      int u = (lane - 16) / 3;
      atomicAdd(&ls[32 + u], val * val);
    }
  }
  __syncthreads();
  if (threadIdx.x < 40) atomicAdd(&stats[threadIdx.x], ls[threadIdx.x]);
}

__global__ __launch_bounds__(256) void node_pass2(
    const float* __restrict__ pre, const float* __restrict__ stats,
    const float* __restrict__ bnws, const float* __restrict__ bnbs,
    const float* __restrict__ bnwv, float* __restrict__ out)
{
  int idx = blockIdx.x * blockDim.x + threadIdx.x;
  if (idx >= NN * 40) return;
  int n = idx / 40;
  int c = idx - n * 40;
  float val = pre[idx];
  constexpr float invN = 1.0f / NN;
  if (c < 16) {
    float mu = stats[c] * invN;
    float var = stats[16 + c] * invN - mu * mu;
    out[idx] = (val - mu) * (rsqrtf(var + EPSV) * bnws[c]) + bnbs[c];
  } else {
    int u = (c - 16) / 3;
    float vn = stats[32 + u] * (invN / 3.0f);
    out[idx] = val * (rsqrtf(vn + EPSV) * bnwv[u]);
  }
}

__global__ __launch_bounds__(256) void copy_ef(const f32x4* __restrict__ src,
                                               f32x4* __restrict__ dst) {
  const int n4 = NE * 64 / 4;
  for (int i = blockIdx.x * blockDim.x + threadIdx.x; i < n4;
       i += gridDim.x * blockDim.x)
    dst[i] = src[i];
}

extern "C" void kernel_launch(void* const* d_in, const int* in_sizes, int n_in,
                              void* d_out, int out_size, void* d_ws, size_t ws_size,
                              hipStream_t stream) {
  (void)in_sizes; (void)n_in; (void)out_size;
  const float* nf   = (const float*)d_in[0];
  const float* ef   = (const float*)d_in[1];
  const float* sh   = (const float*)d_in[2];
  const int*   ei   = (const int*)d_in[3];
  const float* w1   = (const float*)d_in[4];
  const float* b1   = (const float*)d_in[5];
  const float* w2   = (const float*)d_in[6];
  const float* b2   = (const float*)d_in[7];
  const float* bnws = (const float*)d_in[8];
  const float* bnbs = (const float*)d_in[9];
  const float* bnwv = (const float*)d_in[10];

  float* out = (float*)d_out;
  float* efout = out + (size_t)NN * 40;

  // ws layout
  char* w = (char*)d_ws;
  int* deg     = (int*)w;                               // NN      (memset)
  float* stats = (float*)(w + (size_t)NN * 4);          // 48      (memset)
  int* rowoff  = (int*)(w + (size_t)NN * 4 + 192);      // NN+1
  int* wcur    = rowoff + NN + 1;
  int* elist   = wcur + NN;                             // NE
  float* pre   = (float*)(elist + NE);                  // NN*40
  size_t base  = ((size_t)((char*)(pre + (size_t)NN * 40) - w) + 255) & ~(size_t)255;
  short8* w2bf = (short8*)(w + base);                   // 73728 B
  size_t tpoff = (base + SM_W2 + 255) & ~(size_t)255;

  const size_t TPB_F32 = (size_t)NE * 40 * 4;           // 25.6 MB
  const size_t HFB     = (size_t)NT * 128 * 16;         // 20.48 MB
  const size_t needA = tpoff + TPB_F32 + HFB;
  const size_t needB = tpoff + TPB_F32;

  hipMemsetAsync(d_ws, 0, (size_t)NN * 4 + 192, stream);
  hipFuncSetAttribute((const void*)conv_kernel<float>,
                      hipFuncAttributeMaxDynamicSharedMemorySize, SM_TOTAL);
  hipFuncSetAttribute((const void*)conv_kernel<ushort>,
                      hipFuncAttributeMaxDynamicSharedMemorySize, SM_TOTAL);

  prep_w2<<<72, 64, 0, stream>>>(w2, w2bf);

  const int gblocks = 2500;  // gather: 4 nodes/block
  const int pblocks = (NN * 40 + 255) / 256;

  if (ws_size >= needA) {            // Plan A: everything in ws
    float* tp = (float*)(w + tpoff);
    short8* hfrag = (short8*)(w + tpoff + TPB_F32);
    mlp1_kernel<<<2500, 256, 0, stream>>>(ef, w1, b1, hfrag, efout, 1);
    hist_kernel<<<625, 256, 0, stream>>>(ei, deg);
    scan_kernel<<<1, 1024, 0, stream>>>(deg, rowoff, wcur);
    fill_kernel<<<625, 256, 0, stream>>>(ei, wcur, elist);
    conv_kernel<float><<<512, 512, SM_TOTAL, stream>>>(hfrag, w2bf, b2, nf, sh, ei, tp);
    gather_kernel<float><<<gblocks, 256, 0, stream>>>(tp, rowoff, elist, nf, pre, stats);
    node_pass2<<<pblocks, 256, 0, stream>>>(pre, stats, bnws, bnbs, bnwv, out);
  } else if (ws_size >= needB) {     // Plan B: hfrag borrows efout, copy later
    float* tp = (float*)(w + tpoff);
    short8* hfrag = (short8*)efout;
    mlp1_kernel<<<2500, 256, 0, stream>>>(ef, w1, b1, hfrag, efout, 0);
    hist_kernel<<<625, 256, 0, stream>>>(ei, deg);
    scan_kernel<<<1, 1024, 0, stream>>>(deg, rowoff, wcur);
    fill_kernel<<<625, 256, 0, stream>>>(ei, wcur, elist);
    conv_kernel<float><<<512, 512, SM_TOTAL, stream>>>(hfrag, w2bf, b2, nf, sh, ei, tp);
    gather_kernel<float><<<gblocks, 256, 0, stream>>>(tp, rowoff, elist, nf, pre, stats);
    node_pass2<<<pblocks, 256, 0, stream>>>(pre, stats, bnws, bnbs, bnwv, out);
    copy_ef<<<2048, 256, 0, stream>>>((const f32x4*)ef, (f32x4*)efout);
  } else {                           // Plan D: bf16 tp + hfrag both in efout region
    ushort* tp = (ushort*)efout;                              // 12.8 MB
    short8* hfrag = (short8*)((char*)efout + (size_t)NE * 40 * 2);
    mlp1_kernel<<<2500, 256, 0, stream>>>(ef, w1, b1, hfrag, efout, 0);
    hist_kernel<<<625, 256, 0, stream>>>(ei, deg);
    scan_kernel<<<1, 1024, 0, stream>>>(deg, rowoff, wcur);
    fill_kernel<<<625, 256, 0, stream>>>(ei, wcur, elist);
    conv_kernel<ushort><<<512, 512, SM_TOTAL, stream>>>(hfrag, w2bf, b2, nf, sh, ei, tp);
    gather_kernel<ushort><<<gblocks, 256, 0, stream>>>(tp, rowoff, elist, nf, pre, stats);
    node_pass2<<<pblocks, 256, 0, stream>>>(pre, stats, bnws, bnbs, bnwv, out);
    copy_ef<<<2048, 256, 0, stream>>>((const f32x4*)ef, (f32x4*)efout);
  }
}